// Round 10
// baseline (177.793 us; speedup 1.0000x reference)
//
#include <hip/hip_runtime.h>
#include <math.h>

constexpr int L_ = 2048, D_ = 128, H_ = 16;
constexpr int T_ = 8192;
constexpr int DIN = 80;
constexpr int LDX = T_;              // col-major activations act[chan][token]

// ---- static device globals ----
__device__ float g_xT  [DIN * T_];          // [80][8192]
__device__ float g_posT[D_ * L_];           // [128][2048]
__device__ float g_h   [D_ * T_];           // col-major
__device__ float g_qkv [3 * D_ * T_];       // col-major [384][8192]
__device__ float g_ctx [D_ * T_];
__device__ float g_WconvT[DIN * D_];        // [k][o]
__device__ float g_WqkvT [D_ * 3 * D_];     // [128][384]
__device__ float g_Wf1T  [D_ * D_];         // fused (W1*Wo)^T  [d][f]
__device__ float g_WfcT  [D_ * D_];         // fused (Wfc*W2)^T [f][o], o>=80 zero
__device__ float g_bf1   [D_];
__device__ float g_bfc   [D_];

// ---------------------------------------------------------------------------
// prep (verbatim round-8, proven): xT transpose | posenc | weight transposes
// | folds. grid 1000 x 256.
// ---------------------------------------------------------------------------
__global__ __launch_bounds__(256) void prep_kernel(
        const float* __restrict__ x,
        const float* __restrict__ conv_w,
        const float* __restrict__ in_proj_w,
        const float* __restrict__ out_w,  const float* __restrict__ out_b,
        const float* __restrict__ ff_w1,  const float* __restrict__ ff_b1,
        const float* __restrict__ ff_w2,  const float* __restrict__ ff_b2,
        const float* __restrict__ fc_w,   const float* __restrict__ fc_b) {
    __shared__ float smem[80 * 65];
    int bid = blockIdx.x, tid = threadIdx.x;

    if (bid < 128) {                           // x [8192][80] -> xT [80][8192]
        int t0 = bid * 64;
        for (int i = tid; i < 64 * 80; i += 256) {
            int t = i / 80, k = i - t * 80;
            smem[k * 65 + t] = x[(size_t)t0 * 80 + i];
        }
        __syncthreads();
        for (int i = tid; i < 80 * 64; i += 256) {
            int k = i >> 6, tt = i & 63;
            g_xT[(size_t)k * T_ + t0 + tt] = smem[k * 65 + tt];
        }
        return;
    }
    if (bid < 640) {                           // posenc fp32
        int idx = (bid - 128) * 256 + tid;     // [0, 131072)
        int l = idx >> 6, j = idx & 63;
        float inv = __expf((float)j * (-9.210340371976184f / 128.0f));
        float ang = (float)l * inv;
        g_posT[(2 * j) * L_ + l]     = sinf(ang);
        g_posT[(2 * j + 1) * L_ + l] = cosf(ang);
        return;
    }
    if (bid < 680) {                           // conv_w [128][80] -> [80][128]
        int e = (bid - 640) * 256 + tid;
        int o = e / 80, k = e - o * 80;
        g_WconvT[k * D_ + o] = conv_w[e];
        return;
    }
    if (bid < 872) {                           // in_proj_w [384][128] -> [128][384]
        int e = (bid - 680) * 256 + tid;
        int o = e >> 7, k = e & 127;
        g_WqkvT[k * (3 * D_) + o] = in_proj_w[e];
        return;
    }
    float* rowbuf = smem;                      // [2][128]
    float* red = smem + 256;                   // [256]
    if (bid < 936) {                           // fold1: M1=W1*Wo, b1'=W1*bo+b1
        int sub = tid >> 7, k = tid & 127;
        int f = (bid - 872) * 2 + sub;
        rowbuf[sub * 128 + k] = ff_w1[f * 128 + k];
        __syncthreads();
        float acc = 0.f;
#pragma unroll 8
        for (int o = 0; o < 128; o++)
            acc = fmaf(rowbuf[sub * 128 + o], out_w[o * 128 + k], acc);
        g_Wf1T[k * 128 + f] = acc;
        red[tid] = rowbuf[sub * 128 + k] * out_b[k];
        __syncthreads();
        for (int s = 64; s > 0; s >>= 1) {
            if (k < s) red[tid] += red[tid + s];
            __syncthreads();
        }
        if (k == 0) g_bf1[f] = red[sub * 128] + ff_b1[f];
        return;
    }
    {                                          // fold2: M2=Wfc*W2, b2'=Wfc*b2+bfc
        int sub = tid >> 7, k = tid & 127;
        int o = (bid - 936) * 2 + sub;
        rowbuf[sub * 128 + k] = (o < 80) ? fc_w[o * 128 + k] : 0.f;
        __syncthreads();
        float acc = 0.f;
#pragma unroll 8
        for (int d = 0; d < 128; d++)
            acc = fmaf(rowbuf[sub * 128 + d], ff_w2[d * 128 + k], acc);
        g_WfcT[k * 128 + o] = acc;
        red[tid] = rowbuf[sub * 128 + k] * ff_b2[k];
        __syncthreads();
        for (int s = 64; s > 0; s >>= 1) {
            if (k < s) red[tid] += red[tid + s];
            __syncthreads();
        }
        if (k == 0) g_bfc[o] = (o < 80) ? (red[sub * 128] + fc_b[o]) : 0.f;
        return;
    }
}

// ---------------------------------------------------------------------------
// conv GEMM (round-8 template, TN=4 float4 W-read): BM=64 x BN=64, 256 thr.
// EPI=2: relu + BN + posenc from g_posT. grid (128, 2) = 256 blocks.
// ---------------------------------------------------------------------------
template <int K, int BK, int BN, int LDW, int EPI>
__global__ __launch_bounds__(256) void gemm_kernel(
        const float* __restrict__ X, const float* __restrict__ Wt,
        const float* __restrict__ bias,
        const float* __restrict__ bg, const float* __restrict__ bb,
        const float* __restrict__ brm, const float* __restrict__ brv,
        float* __restrict__ Y) {
    constexpr int TN = BN / 16;
    __shared__ float Xs[BK][64];
    __shared__ float Ws[BK][BN];
    int tid = threadIdx.x;
    int t0 = blockIdx.x * 64;
    int cb = blockIdx.y * BN;
    int tc = tid & 15, tr = tid >> 4;

    float acc[4][TN] = {};
    for (int kc = 0; kc < K; kc += BK) {
        for (int i = tid; i < BK * 16; i += 256) {
            int k = i >> 4, f = i & 15;
            *(float4*)&Xs[k][f * 4] =
                *(const float4*)&X[(size_t)(kc + k) * LDX + t0 + f * 4];
        }
        for (int i = tid; i < BK * (BN / 4); i += 256) {
            int k = i / (BN / 4), f = i - k * (BN / 4);
            *(float4*)&Ws[k][f * 4] =
                *(const float4*)&Wt[(size_t)(kc + k) * LDW + cb + f * 4];
        }
        __syncthreads();
#pragma unroll 4
        for (int k = 0; k < BK; ++k) {
            float4 a = *(float4*)&Xs[k][tr * 4];
            float av[4] = {a.x, a.y, a.z, a.w};
            float wv[TN];
            if (TN == 4) {
                float4 w = *(float4*)&Ws[k][tc * 4];
                wv[0] = w.x; wv[1] = w.y; wv[2] = w.z; wv[3] = w.w;
            } else {
#pragma unroll
                for (int jj = 0; jj < TN; jj++) wv[jj] = Ws[k][tc * TN + jj];
            }
#pragma unroll
            for (int i = 0; i < 4; i++)
#pragma unroll
                for (int jj = 0; jj < TN; jj++)
                    acc[i][jj] = fmaf(av[i], wv[jj], acc[i][jj]);
        }
        __syncthreads();
    }

#pragma unroll
    for (int jj = 0; jj < TN; jj++) {
        int c = cb + tc * TN + jj;
        float bv = bias[c];
        float vs[4];
#pragma unroll
        for (int i = 0; i < 4; i++) {
            float v = acc[i][jj] + bv;
            if (EPI == 1) v = fmaxf(v, 0.0f);
            if (EPI == 2) {
                v = fmaxf(v, 0.0f);
                v = (v - brm[c]) * (bg[c] * rsqrtf(brv[c] + 1e-5f)) + bb[c];
                v += g_posT[c * L_ + ((t0 & 2047) + tr * 4 + i)];
            }
            vs[i] = v;
        }
        *(float4*)&Y[(size_t)c * LDX + t0 + tr * 4] = *(float4*)vs;
    }
}

// ---------------------------------------------------------------------------
// qkv: K=128, tile 128 tokens x 64 cols, TM=8 x TN=4, BK=64, W pre-transposed
// in prep (conflict-free float4 staging). grid (64, 6) = 384 blocks.
// ---------------------------------------------------------------------------
__global__ __launch_bounds__(256) void qkv_kernel(const float* __restrict__ in_proj_b) {
    __shared__ float Xs[64 * 128];               // [k][t] 32 KB
    __shared__ float Ws[64 * 64];                // [k][c] 16 KB
    int tid = threadIdx.x;
    int t0 = blockIdx.x * 128;
    int cb = blockIdx.y * 64;
    int tc = tid & 15, tr = tid >> 4;

    float acc[8][4] = {};
    for (int kc = 0; kc < 128; kc += 64) {
        for (int i = tid; i < 64 * 32; i += 256) {   // h col-major -> Xs[k][t]
            int k = i >> 5, f = i & 31;
            *(float4*)&Xs[k * 128 + f * 4] =
                *(const float4*)&g_h[(size_t)(kc + k) * LDX + t0 + f * 4];
        }
        for (int i = tid; i < 64 * 16; i += 256) {   // WqkvT -> Ws[k][c-local]
            int k = i >> 4, f = i & 15;
            *(float4*)&Ws[k * 64 + f * 4] =
                *(const float4*)&g_WqkvT[(size_t)(kc + k) * 384 + cb + f * 4];
        }
        __syncthreads();
#pragma unroll 4
        for (int k = 0; k < 64; k++) {
            float4 a0 = *(float4*)&Xs[k * 128 + tr * 8];
            float4 a1 = *(float4*)&Xs[k * 128 + tr * 8 + 4];
            float4 w  = *(float4*)&Ws[k * 64 + tc * 4];
            float av[8] = {a0.x, a0.y, a0.z, a0.w, a1.x, a1.y, a1.z, a1.w};
            float wv[4] = {w.x, w.y, w.z, w.w};
#pragma unroll
            for (int i = 0; i < 8; i++)
#pragma unroll
                for (int jj = 0; jj < 4; jj++)
                    acc[i][jj] = fmaf(av[i], wv[jj], acc[i][jj]);
        }
        __syncthreads();
    }

#pragma unroll
    for (int jj = 0; jj < 4; jj++) {
        int C = cb + tc * 4 + jj;
        float bv = in_proj_b[C];
        float vs[8];
#pragma unroll
        for (int i = 0; i < 8; i++) vs[i] = acc[i][jj] + bv;
        *(float4*)&g_qkv[(size_t)C * LDX + t0 + tr * 8]     = *(float4*)&vs[0];
        *(float4*)&g_qkv[(size_t)C * LDX + t0 + tr * 8 + 4] = *(float4*)&vs[4];
    }
}

// ---------------------------------------------------------------------------
// Attention (verbatim round-8, proven). Block = (bh, 512-q tile), 256 thr,
// 2 adjacent q/thread, parity-split float4 staging, writes ctx col-major.
// ---------------------------------------------------------------------------
__global__ __launch_bounds__(256) void attn_kernel() {
    __shared__ float4 SK[2][2][324];
    __shared__ float4 SV[2][2][324];
    int bh = blockIdx.x;
    int qb = blockIdx.y * 512;
    int b = bh >> 4, h = bh & 15;
    int tb = b * L_;
    int tid = threadIdx.x;
    int jbase = qb - 64;

    for (int c16 = 0; c16 < 16; c16++) {
        int d = c16 & 7;
        int ch = ((c16 < 8) ? D_ : 2 * D_) + h * 8 + d;
        const float* src = g_qkv + (size_t)ch * LDX + tb;
        float4* base4 = ((c16 < 8) ? &SK[0][0][0] : &SV[0][0][0]) + (d >> 2) * 324;
        for (int s = tid; s < 641; s += 256) {
            int j = jbase + s;
            float v = ((unsigned)j < (unsigned)L_) ? src[j] : 0.f;
            ((float*)(base4 + (s & 1) * 648 + (s >> 1)))[d & 3] = v;
        }
    }
    __syncthreads();

    const float sc = 0.35355339059327373f;      // 1/sqrt(8)
    int q0 = qb + 2 * tid;
    float qa[8], qc[8];
#pragma unroll
    for (int d = 0; d < 8; d++) {
        qa[d] = g_qkv[(size_t)(h * 8 + d) * LDX + tb + q0] * sc;
        qc[d] = g_qkv[(size_t)(h * 8 + d) * LDX + tb + q0 + 1] * sc;
    }
    float l0 = 0.f, l1 = 0.f;
    float A0[8] = {}, A1[8] = {};
    int j00 = jbase + 2 * tid;

#pragma unroll 2
    for (int it = 0; it <= 129; it++) {
        int pp = it & 1, idx = tid + (it >> 1);
        float4 ka = SK[pp][0][idx], kb2 = SK[pp][1][idx];
        float kv[8] = {ka.x, ka.y, ka.z, ka.w, kb2.x, kb2.y, kb2.z, kb2.w};
        float s0 = 0.f, s1 = 0.f;
#pragma unroll
        for (int d = 0; d < 8; d++) {
            s0 = fmaf(qa[d], kv[d], s0);
            s1 = fmaf(qc[d], kv[d], s1);
        }
        bool jv = (unsigned)(j00 + it) < (unsigned)L_;
        float w0 = (jv && it != 64 && it <= 128) ? __expf(s0) : 0.f;
        float w1 = (jv && it != 65 && it >= 1)  ? __expf(s1) : 0.f;
        l0 += w0; l1 += w1;
        float4 va = SV[pp][0][idx], vb2 = SV[pp][1][idx];
        float vv[8] = {va.x, va.y, va.z, va.w, vb2.x, vb2.y, vb2.z, vb2.w};
#pragma unroll
        for (int d = 0; d < 8; d++) {
            A0[d] = fmaf(w0, vv[d], A0[d]);
            A1[d] = fmaf(w1, vv[d], A1[d]);
        }
    }
    float i0 = 1.f / l0, i1 = 1.f / l1;
    int base = tb + q0;
#pragma unroll
    for (int d = 0; d < 8; d++) {
        g_ctx[(size_t)(h * 8 + d) * LDX + base]     = A0[d] * i0;
        g_ctx[(size_t)(h * 8 + d) * LDX + base + 1] = A1[d] * i1;
    }
}

// ---------------------------------------------------------------------------
// Fused tail (verbatim round-9, proven): f1=relu(ctx*M1^T+b1') in LDS, then
// out = f1*M2^T + b2' row-major [t][80]. Block = 32 tokens. 256 blocks.
// ---------------------------------------------------------------------------
__global__ __launch_bounds__(256) void f1fc_kernel(float* __restrict__ out) {
    __shared__ float Xs[128 * 32];
    __shared__ float Wsh[32 * 128];
    __shared__ float F[128 * 36];
    int tid = threadIdx.x;
    int t0 = blockIdx.x * 32;
    int tc = tid & 31, tr = tid >> 5;

    for (int i = tid; i < 128 * 8; i += 256) {   // ctx -> Xs[k][t]
        int k = i >> 3, f = i & 7;
        *(float4*)&Xs[k * 32 + f * 4] =
            *(const float4*)&g_ctx[(size_t)k * LDX + t0 + f * 4];
    }

    float acc[4][4] = {};
    for (int kc = 0; kc < 128; kc += 32) {
        for (int i = tid; i < 32 * 32; i += 256) {
            int k = i >> 5, f = i & 31;
            *(float4*)&Wsh[k * 128 + f * 4] =
                *(const float4*)&g_Wf1T[(size_t)(kc + k) * 128 + f * 4];
        }
        __syncthreads();
#pragma unroll 4
        for (int k = 0; k < 32; k++) {
            float4 a = *(float4*)&Xs[(kc + k) * 32 + tr * 4];
            float4 w = *(float4*)&Wsh[k * 128 + tc * 4];
            float av[4] = {a.x, a.y, a.z, a.w};
            float wv[4] = {w.x, w.y, w.z, w.w};
#pragma unroll
            for (int i = 0; i < 4; i++)
#pragma unroll
                for (int jj = 0; jj < 4; jj++)
                    acc[i][jj] = fmaf(av[i], wv[jj], acc[i][jj]);
        }
        __syncthreads();
    }
#pragma unroll
    for (int jj = 0; jj < 4; jj++) {             // relu + bias -> F[f][t]
        int c = tc * 4 + jj;
        float bv = g_bf1[c];
#pragma unroll
        for (int i = 0; i < 4; i++)
            F[c * 36 + tr * 4 + i] = fmaxf(acc[i][jj] + bv, 0.f);
    }
    __syncthreads();

    float acc2[4][4] = {};
    for (int kc = 0; kc < 128; kc += 32) {
        for (int i = tid; i < 32 * 32; i += 256) {
            int k = i >> 5, f = i & 31;
            *(float4*)&Wsh[k * 128 + f * 4] =
                *(const float4*)&g_WfcT[(size_t)(kc + k) * 128 + f * 4];
        }
        __syncthreads();
#pragma unroll 4
        for (int k = 0; k < 32; k++) {
            float4 a = *(float4*)&F[(kc + k) * 36 + tr * 4];
            float4 w = *(float4*)&Wsh[k * 128 + tc * 4];
            float av[4] = {a.x, a.y, a.z, a.w};
            float wv[4] = {w.x, w.y, w.z, w.w};
#pragma unroll
            for (int i = 0; i < 4; i++)
#pragma unroll
                for (int jj = 0; jj < 4; jj++)
                    acc2[i][jj] = fmaf(av[i], wv[jj], acc2[i][jj]);
        }
        __syncthreads();
    }
    if (tc < 20) {                               // cols 0..79 only
#pragma unroll
        for (int i = 0; i < 4; i++) {
            int t = t0 + tr * 4 + i;
            float vs[4];
#pragma unroll
            for (int jj = 0; jj < 4; jj++) vs[jj] = acc2[i][jj] + g_bfc[tc * 4 + jj];
            *(float4*)&out[(size_t)t * 80 + tc * 4] = *(float4*)vs;
        }
    }
}

// ---------------------------------------------------------------------------
extern "C" void kernel_launch(void* const* d_in, const int* in_sizes, int n_in,
                              void* d_out, int out_size, void* d_ws, size_t ws_size,
                              hipStream_t stream) {
    const float* x         = (const float*)d_in[0];
    const float* conv_w    = (const float*)d_in[1];
    const float* conv_b    = (const float*)d_in[2];
    const float* bn_g      = (const float*)d_in[3];
    const float* bn_b      = (const float*)d_in[4];
    const float* bn_rm     = (const float*)d_in[5];
    const float* bn_rv     = (const float*)d_in[6];
    const float* in_proj_w = (const float*)d_in[7];
    const float* in_proj_b = (const float*)d_in[8];
    const float* out_w     = (const float*)d_in[9];
    const float* out_b     = (const float*)d_in[10];
    const float* ff_w1     = (const float*)d_in[11];
    const float* ff_b1     = (const float*)d_in[12];
    const float* ff_w2     = (const float*)d_in[13];
    const float* ff_b2     = (const float*)d_in[14];
    const float* fc_w      = (const float*)d_in[15];
    const float* fc_b      = (const float*)d_in[16];

    float *p_xT, *p_h, *p_WconvT;
    hipGetSymbolAddress((void**)&p_xT,     HIP_SYMBOL(g_xT));
    hipGetSymbolAddress((void**)&p_h,      HIP_SYMBOL(g_h));
    hipGetSymbolAddress((void**)&p_WconvT, HIP_SYMBOL(g_WconvT));

    prep_kernel<<<1000, 256, 0, stream>>>(x, conv_w, in_proj_w, out_w, out_b,
                                          ff_w1, ff_b1, ff_w2, ff_b2, fc_w, fc_b);

    // conv+relu+bn+pos: K=80, BN=64 (TN=4), 256 blocks
    gemm_kernel<80, 80, 64, 128, 2><<<dim3(128, 2), 256, 0, stream>>>(
        p_xT, p_WconvT, conv_b, bn_g, bn_b, bn_rm, bn_rv, p_h);

    // qkv: TM=8, prep-transposed W, 384 blocks
    qkv_kernel<<<dim3(64, 6), 256, 0, stream>>>(in_proj_b);

    // full-window attention -> ctx, 256 blocks
    attn_kernel<<<dim3(64, 4), 256, 0, stream>>>();

    // fused out_proj+ff1+ff2+fc -> row-major [t][80], 256 blocks
    f1fc_kernel<<<256, 256, 0, stream>>>((float*)d_out);
}

// Round 11
// 163.159 us; speedup vs baseline: 1.0897x; 1.0897x over previous
//
#include <hip/hip_runtime.h>
#include <math.h>

constexpr int L_ = 2048, D_ = 128, H_ = 16;
constexpr int T_ = 8192;
constexpr int DIN = 80;
constexpr int LDX = T_;              // col-major activations act[chan][token]
constexpr int BHL = 131072;          // B*H*L

typedef __attribute__((ext_vector_type(8))) short short8;   // 8 bf16 (4 VGPR)
typedef __attribute__((ext_vector_type(4))) float floatx4;

// ---- static device globals ----
__device__ float g_xT  [DIN * T_];          // [80][8192]
__device__ float g_posT[D_ * L_];           // [128][2048]
__device__ unsigned short g_h_hi[T_ * D_];  // h bf16-hi, ROW-major [t][k]
__device__ unsigned short g_h_lo[T_ * D_];  // h residual lo
__device__ unsigned short g_Wq_hi[3 * D_ * D_];  // in_proj_w bf16x2, row-major [c][k]
__device__ unsigned short g_Wq_lo[3 * D_ * D_];
__device__ float g_qkv [3 * D_ * T_];       // col-major [384][8192]
__device__ float g_ctx [D_ * T_];
__device__ float g_f1  [D_ * T_];
__device__ float g_pA  [2 * 8 * BHL];       // attn partials [half][d][bh*2048+l]
__device__ float g_pl  [2 * BHL];
__device__ float g_WconvT[DIN * D_];        // [k][o]
__device__ float g_Wf1T  [D_ * D_];         // fused (W1*Wo)^T  [d][f]
__device__ float g_WfcT  [D_ * D_];         // fused (Wfc*W2)^T [f][o], o>=80 zero
__device__ float g_bf1   [D_];
__device__ float g_bfc   [D_];

__device__ __forceinline__ unsigned short bf16h(float x) {      // RNE to bf16
    unsigned u = __float_as_uint(x);
    return (unsigned short)((u + 0x7FFFu + ((u >> 16) & 1u)) >> 16);
}
__device__ __forceinline__ float bf16f(unsigned short h) {
    return __uint_as_float(((unsigned)h) << 16);
}

// ---------------------------------------------------------------------------
// prep (R6 structure): xT transpose | posenc | conv_w transpose |
// in_proj_w -> bf16x2 (row-major, NO transpose) | folds.  grid 1000 x 256.
// ---------------------------------------------------------------------------
__global__ __launch_bounds__(256) void prep_kernel(
        const float* __restrict__ x,
        const float* __restrict__ conv_w,
        const float* __restrict__ in_proj_w,
        const float* __restrict__ out_w,  const float* __restrict__ out_b,
        const float* __restrict__ ff_w1,  const float* __restrict__ ff_b1,
        const float* __restrict__ ff_w2,  const float* __restrict__ ff_b2,
        const float* __restrict__ fc_w,   const float* __restrict__ fc_b) {
    __shared__ float smem[80 * 65];
    int bid = blockIdx.x, tid = threadIdx.x;

    if (bid < 128) {                           // x [8192][80] -> xT [80][8192]
        int t0 = bid * 64;
        for (int i = tid; i < 64 * 80; i += 256) {
            int t = i / 80, k = i - t * 80;
            smem[k * 65 + t] = x[(size_t)t0 * 80 + i];
        }
        __syncthreads();
        for (int i = tid; i < 80 * 64; i += 256) {
            int k = i >> 6, tt = i & 63;
            g_xT[(size_t)k * T_ + t0 + tt] = smem[k * 65 + tt];
        }
        return;
    }
    if (bid < 640) {                           // posenc fp32
        int idx = (bid - 128) * 256 + tid;     // [0, 131072)
        int l = idx >> 6, j = idx & 63;
        float inv = __expf((float)j * (-9.210340371976184f / 128.0f));
        float ang = (float)l * inv;
        g_posT[(2 * j) * L_ + l]     = sinf(ang);
        g_posT[(2 * j + 1) * L_ + l] = cosf(ang);
        return;
    }
    if (bid < 680) {                           // conv_w [128][80] -> [80][128]
        int e = (bid - 640) * 256 + tid;
        int o = e / 80, k = e - o * 80;
        g_WconvT[k * D_ + o] = conv_w[e];
        return;
    }
    if (bid < 872) {                           // in_proj_w -> bf16x2 elementwise
        int e = (bid - 680) * 256 + tid;       // [0, 49152)
        float v = in_proj_w[e];
        unsigned short hi = bf16h(v);
        g_Wq_hi[e] = hi;
        g_Wq_lo[e] = bf16h(v - bf16f(hi));
        return;
    }
    float* rowbuf = smem;                      // [2][128]
    float* red = smem + 256;                   // [256]
    if (bid < 936) {                           // fold1: M1=W1*Wo, b1'=W1*bo+b1
        int sub = tid >> 7, k = tid & 127;
        int f = (bid - 872) * 2 + sub;
        rowbuf[sub * 128 + k] = ff_w1[f * 128 + k];
        __syncthreads();
        float acc = 0.f;
#pragma unroll 8
        for (int o = 0; o < 128; o++)
            acc = fmaf(rowbuf[sub * 128 + o], out_w[o * 128 + k], acc);
        g_Wf1T[k * 128 + f] = acc;
        red[tid] = rowbuf[sub * 128 + k] * out_b[k];
        __syncthreads();
        for (int s = 64; s > 0; s >>= 1) {
            if (k < s) red[tid] += red[tid + s];
            __syncthreads();
        }
        if (k == 0) g_bf1[f] = red[sub * 128] + ff_b1[f];
        return;
    }
    {                                          // fold2: M2=Wfc*W2, b2'=Wfc*b2+bfc
        int sub = tid >> 7, k = tid & 127;
        int o = (bid - 936) * 2 + sub;
        rowbuf[sub * 128 + k] = (o < 80) ? fc_w[o * 128 + k] : 0.f;
        __syncthreads();
        float acc = 0.f;
#pragma unroll 8
        for (int d = 0; d < 128; d++)
            acc = fmaf(rowbuf[sub * 128 + d], ff_w2[d * 128 + k], acc);
        g_WfcT[k * 128 + o] = acc;
        red[tid] = rowbuf[sub * 128 + k] * ff_b2[k];
        __syncthreads();
        for (int s = 64; s > 0; s >>= 1) {
            if (k < s) red[tid] += red[tid + s];
            __syncthreads();
        }
        if (k == 0) g_bfc[o] = (o < 80) ? (red[sub * 128] + fc_b[o]) : 0.f;
        return;
    }
}

// ---------------------------------------------------------------------------
// fp32 GEMM (R6 template): BM=64 x BN, 256 thr 16x16, TM=4 x TN=BN/16.
// EPI: 1 relu col-major, 4 fc row-major [t][80],
//      5 conv: relu+bn+posenc then bf16x2 ROW-major h (TN==2 path)
// ---------------------------------------------------------------------------
template <int K, int BK, int BN, int LDW, int EPI>
__global__ __launch_bounds__(256) void gemm_kernel(
        const float* __restrict__ X, const float* __restrict__ Wt,
        const float* __restrict__ bias,
        const float* __restrict__ bg, const float* __restrict__ bb,
        const float* __restrict__ brm, const float* __restrict__ brv,
        float* __restrict__ Y) {
    constexpr int TN = BN / 16;
    __shared__ float Xs[BK][64];
    __shared__ float Ws[BK][BN];
    int tid = threadIdx.x;
    int t0 = blockIdx.x * 64;
    int cb = blockIdx.y * BN;
    int tc = tid & 15, tr = tid >> 4;

    float acc[4][TN] = {};
    for (int kc = 0; kc < K; kc += BK) {
        for (int i = tid; i < BK * 16; i += 256) {
            int k = i >> 4, f = i & 15;
            *(float4*)&Xs[k][f * 4] =
                *(const float4*)&X[(size_t)(kc + k) * LDX + t0 + f * 4];
        }
        for (int i = tid; i < BK * (BN / 4); i += 256) {
            int k = i / (BN / 4), f = i - k * (BN / 4);
            *(float4*)&Ws[k][f * 4] =
                *(const float4*)&Wt[(size_t)(kc + k) * LDW + cb + f * 4];
        }
        __syncthreads();
#pragma unroll 4
        for (int k = 0; k < BK; ++k) {
            float4 a = *(float4*)&Xs[k][tr * 4];
            float av[4] = {a.x, a.y, a.z, a.w};
            float wv[TN];
#pragma unroll
            for (int jj = 0; jj < TN; jj++) wv[jj] = Ws[k][tc * TN + jj];
#pragma unroll
            for (int i = 0; i < 4; i++)
#pragma unroll
                for (int jj = 0; jj < TN; jj++)
                    acc[i][jj] = fmaf(av[i], wv[jj], acc[i][jj]);
        }
        __syncthreads();
    }

    if (EPI == 5) {                            // conv -> bf16x2 row-major h
#pragma unroll
        for (int i = 0; i < 4; i++) {
            int t = t0 + tr * 4 + i;
            unsigned hi2 = 0, lo2 = 0;
#pragma unroll
            for (int jj = 0; jj < TN; jj++) {
                int c = cb + tc * TN + jj;
                float v = acc[i][jj] + bias[c];
                v = fmaxf(v, 0.0f);
                v = (v - brm[c]) * (bg[c] * rsqrtf(brv[c] + 1e-5f)) + bb[c];
                v += g_posT[c * L_ + (t & 2047)];
                unsigned short h = bf16h(v);
                float lo = v - bf16f(h);
                hi2 |= ((unsigned)h) << (16 * jj);
                lo2 |= ((unsigned)bf16h(lo)) << (16 * jj);
            }
            int cbase = cb + tc * TN;          // TN==2: one dword per array
            *(unsigned*)&g_h_hi[(size_t)t * 128 + cbase] = hi2;
            *(unsigned*)&g_h_lo[(size_t)t * 128 + cbase] = lo2;
        }
        return;
    }
    if (EPI == 4) {                            // row-major [t][80]
#pragma unroll
        for (int jj = 0; jj < TN; jj++) {
            int c = cb + tc * TN + jj;
            if (c < 80) {
                float bv = bias[c];
#pragma unroll
                for (int i = 0; i < 4; i++) {
                    int t = t0 + tr * 4 + i;
                    Y[(size_t)t * 80 + c] = acc[i][jj] + bv;
                }
            }
        }
        return;
    }
#pragma unroll
    for (int jj = 0; jj < TN; jj++) {
        int c = cb + tc * TN + jj;
        float bv = bias[c];
        float vs[4];
#pragma unroll
        for (int i = 0; i < 4; i++) {
            float v = acc[i][jj] + bv;
            if (EPI == 1) v = fmaxf(v, 0.0f);
            vs[i] = v;
        }
        *(float4*)&Y[(size_t)c * LDX + t0 + tr * 4] = *(float4*)vs;
    }
}

// ---------------------------------------------------------------------------
// qkv via MFMA bf16x2: C[c][t] = sum_k W[c][k]*h[t][k] (+bias), fp32 out.
// Block: 32 tokens x 64-col slab, 256 thr = 4 waves (wave = 16-col subtile).
// A = W (row-major frags), B = h rows (row-major frags). 3 MFMA per k-tile
// (hh, lh, hl). Layouts: A[m=lane&15][k=quad*8+j] (guide m120-verified),
// B[k=quad*8+j][n=lane&15], D col=lane&15 row=quad*4+reg (m89-verified).
// grid (256, 6) = 1536 blocks, LDS 52 KB, ~3 blocks/CU.
// ---------------------------------------------------------------------------
__global__ __launch_bounds__(256) void qkv_mfma(const float* __restrict__ in_proj_b) {
    __shared__ unsigned short WsH[64 * 136];   // pitch 136 (272 B, 16B-aligned)
    __shared__ unsigned short WsL[64 * 136];
    __shared__ unsigned short HsH[32 * 136];
    __shared__ unsigned short HsL[32 * 136];
    int tid = threadIdx.x;
    int t0 = blockIdx.x * 32;
    int cb = blockIdx.y * 64;

    for (int i = tid; i < 1024; i += 256) {    // W planes: 64 rows x 16 chunks
        int r = i >> 4, c8 = (i & 15) * 8;
        *(uint4*)&WsH[r * 136 + c8] = *(const uint4*)&g_Wq_hi[(size_t)(cb + r) * 128 + c8];
        *(uint4*)&WsL[r * 136 + c8] = *(const uint4*)&g_Wq_lo[(size_t)(cb + r) * 128 + c8];
    }
    for (int i = tid; i < 512; i += 256) {     // H planes: 32 rows x 16 chunks
        int r = i >> 4, c8 = (i & 15) * 8;
        *(uint4*)&HsH[r * 136 + c8] = *(const uint4*)&g_h_hi[(size_t)(t0 + r) * 128 + c8];
        *(uint4*)&HsL[r * 136 + c8] = *(const uint4*)&g_h_lo[(size_t)(t0 + r) * 128 + c8];
    }
    __syncthreads();

    int lane = tid & 63, w = tid >> 6;
    int m16 = lane & 15, quad = lane >> 4;
    int c0 = w * 16;                           // wave's col-subtile in slab

    short8 aH[4], aL[4];
#pragma unroll
    for (int kt = 0; kt < 4; kt++) {
        aH[kt] = *(short8*)&WsH[(c0 + m16) * 136 + kt * 32 + quad * 8];
        aL[kt] = *(short8*)&WsL[(c0 + m16) * 136 + kt * 32 + quad * 8];
    }
    float bias_r[4];
#pragma unroll
    for (int r = 0; r < 4; r++) bias_r[r] = in_proj_b[cb + c0 + quad * 4 + r];

#pragma unroll
    for (int s = 0; s < 2; s++) {              // two 16-token subtiles
        floatx4 acc = {0.f, 0.f, 0.f, 0.f};
        int trow = s * 16 + m16;
#pragma unroll
        for (int kt = 0; kt < 4; kt++) {
            short8 bH = *(short8*)&HsH[trow * 136 + kt * 32 + quad * 8];
            short8 bL = *(short8*)&HsL[trow * 136 + kt * 32 + quad * 8];
            acc = __builtin_amdgcn_mfma_f32_16x16x32_bf16(aH[kt], bH, acc, 0, 0, 0);
            acc = __builtin_amdgcn_mfma_f32_16x16x32_bf16(aL[kt], bH, acc, 0, 0, 0);
            acc = __builtin_amdgcn_mfma_f32_16x16x32_bf16(aH[kt], bL, acc, 0, 0, 0);
        }
#pragma unroll
        for (int r = 0; r < 4; r++)
            g_qkv[(size_t)(cb + c0 + quad * 4 + r) * LDX + t0 + s * 16 + m16] =
                acc[r] + bias_r[r];
    }
}

// ---------------------------------------------------------------------------
// Attention halves (verbatim R6 champion). Block = (bh, 256-q tile, half).
// 128 thr, 2 adjacent q each. Partials to g_pA/g_pl.
// ---------------------------------------------------------------------------
__global__ __launch_bounds__(128) void attn_kernel() {
    __shared__ float4 SK[2][2][160];
    __shared__ float4 SV[2][2][160];
    int bh = blockIdx.x, tile = blockIdx.y, hf = blockIdx.z;
    int b = bh >> 4, h = bh & 15;
    int qb = tile * 256;
    int tid = threadIdx.x;
    int jbase = hf ? (qb + 1) : (qb - 64);
    int tb = b * L_;

    for (int c16 = 0; c16 < 16; c16++) {       // stage 16 channels x 319 slots
        int d = c16 & 7;
        int ch = ((c16 < 8) ? D_ : 2 * D_) + h * 8 + d;
        const float* src = g_qkv + (size_t)ch * LDX + tb;
        for (int s = tid; s < 319; s += 128) {
            int j = jbase + s;
            float v = ((unsigned)j < (unsigned)L_) ? src[j] : 0.f;
            float4* arr = (c16 < 8) ? &SK[s & 1][d >> 2][s >> 1]
                                    : &SV[s & 1][d >> 2][s >> 1];
            ((float*)arr)[d & 3] = v;
        }
    }
    __syncthreads();

    const float sc = 0.35355339059327373f;     // 1/sqrt(8)
    int q0 = qb + 2 * tid;
    float qa[8], qc[8];
#pragma unroll
    for (int d = 0; d < 8; d++) {
        qa[d] = g_qkv[(size_t)(h * 8 + d) * LDX + tb + q0] * sc;
        qc[d] = g_qkv[(size_t)(h * 8 + d) * LDX + tb + q0 + 1] * sc;
    }

    float l0 = 0.f, l1 = 0.f;
    float A0[8] = {}, A1[8] = {};
    int j00 = jbase + 2 * tid;

    auto step = [&](int it, bool m0, bool m1) {
        int p = it & 1, idx = tid + (it >> 1);
        float4 ka = SK[p][0][idx], kb = SK[p][1][idx];
        float kv[8] = {ka.x, ka.y, ka.z, ka.w, kb.x, kb.y, kb.z, kb.w};
        float s0 = 0.f, s1 = 0.f;
#pragma unroll
        for (int d = 0; d < 8; d++) {
            s0 = fmaf(qa[d], kv[d], s0);
            s1 = fmaf(qc[d], kv[d], s1);
        }
        bool jv = (unsigned)(j00 + it) < (unsigned)L_;
        float w0 = (m0 && jv) ? __expf(s0) : 0.f;
        float w1 = (m1 && jv) ? __expf(s1) : 0.f;
        l0 += w0; l1 += w1;
        float4 va = SV[p][0][idx], vb = SV[p][1][idx];
        float vv[8] = {va.x, va.y, va.z, va.w, vb.x, vb.y, vb.z, vb.w};
#pragma unroll
        for (int d = 0; d < 8; d++) {
            A0[d] = fmaf(w0, vv[d], A0[d]);
            A1[d] = fmaf(w1, vv[d], A1[d]);
        }
    };

    step(0, true, false);                      // it=0: q1 inactive
#pragma unroll 2
    for (int it = 1; it <= 63; it++) step(it, true, true);
    step(64, false, true);                     // it=64: q0 inactive

    int base = bh * L_ + q0;
#pragma unroll
    for (int d = 0; d < 8; d++) {
        g_pA[(size_t)(hf * 8 + d) * BHL + base]     = A0[d];
        g_pA[(size_t)(hf * 8 + d) * BHL + base + 1] = A1[d];
    }
    g_pl[hf * BHL + base]     = l0;
    g_pl[hf * BHL + base + 1] = l1;
}

// combine halves -> ctx col-major (verbatim R6)
__global__ __launch_bounds__(256) void combine_kernel() {
    int gq = blockIdx.x * 256 + threadIdx.x;   // [0, 131072)
    int bh = gq >> 11, l = gq & 2047;
    int b = bh >> 4, h = bh & 15;
    float inv = 1.f / (g_pl[gq] + g_pl[BHL + gq]);
#pragma unroll
    for (int d = 0; d < 8; d++) {
        float v = (g_pA[(size_t)d * BHL + gq] + g_pA[(size_t)(8 + d) * BHL + gq]) * inv;
        g_ctx[(size_t)(h * 8 + d) * LDX + b * L_ + l] = v;
    }
}

// ---------------------------------------------------------------------------
extern "C" void kernel_launch(void* const* d_in, const int* in_sizes, int n_in,
                              void* d_out, int out_size, void* d_ws, size_t ws_size,
                              hipStream_t stream) {
    const float* x         = (const float*)d_in[0];
    const float* conv_w    = (const float*)d_in[1];
    const float* conv_b    = (const float*)d_in[2];
    const float* bn_g      = (const float*)d_in[3];
    const float* bn_b      = (const float*)d_in[4];
    const float* bn_rm     = (const float*)d_in[5];
    const float* bn_rv     = (const float*)d_in[6];
    const float* in_proj_w = (const float*)d_in[7];
    const float* in_proj_b = (const float*)d_in[8];
    const float* out_w     = (const float*)d_in[9];
    const float* out_b     = (const float*)d_in[10];
    const float* ff_w1     = (const float*)d_in[11];
    const float* ff_b1     = (const float*)d_in[12];
    const float* ff_w2     = (const float*)d_in[13];
    const float* ff_b2     = (const float*)d_in[14];
    const float* fc_w      = (const float*)d_in[15];
    const float* fc_b      = (const float*)d_in[16];

    float *p_xT, *p_WconvT, *p_ctx, *p_f1, *p_Wf1T, *p_WfcT, *p_bf1, *p_bfc;
    hipGetSymbolAddress((void**)&p_xT,     HIP_SYMBOL(g_xT));
    hipGetSymbolAddress((void**)&p_WconvT, HIP_SYMBOL(g_WconvT));
    hipGetSymbolAddress((void**)&p_ctx,    HIP_SYMBOL(g_ctx));
    hipGetSymbolAddress((void**)&p_f1,     HIP_SYMBOL(g_f1));
    hipGetSymbolAddress((void**)&p_Wf1T,   HIP_SYMBOL(g_Wf1T));
    hipGetSymbolAddress((void**)&p_WfcT,   HIP_SYMBOL(g_WfcT));
    hipGetSymbolAddress((void**)&p_bf1,    HIP_SYMBOL(g_bf1));
    hipGetSymbolAddress((void**)&p_bfc,    HIP_SYMBOL(g_bfc));

    prep_kernel<<<1000, 256, 0, stream>>>(x, conv_w, in_proj_w, out_w, out_b,
                                          ff_w1, ff_b1, ff_w2, ff_b2, fc_w, fc_b);

    // conv+relu+bn+pos -> h bf16x2 row-major: K=80, BN=32, 512 blocks
    gemm_kernel<80, 80, 32, 128, 5><<<dim3(128, 4), 256, 0, stream>>>(
        p_xT, p_WconvT, conv_b, bn_g, bn_b, bn_rm, bn_rv, nullptr);

    // qkv via MFMA bf16x2: 1536 blocks
    qkv_mfma<<<dim3(256, 6), 256, 0, stream>>>(in_proj_b);

    // attention halves (1024 blocks) + combine (512)
    attn_kernel<<<dim3(64, 8, 2), 128, 0, stream>>>();
    combine_kernel<<<512, 256, 0, stream>>>();

    // fused out_proj+ff1: relu(ctx*M1^T + b1'), 512 blocks
    gemm_kernel<128, 128, 32, 128, 1><<<dim3(128, 4), 256, 0, stream>>>(
        p_ctx, p_Wf1T, p_bf1, nullptr, nullptr, nullptr, nullptr, p_f1);

    // fused ff2+fc -> row-major [t][80], 384 blocks
    gemm_kernel<128, 128, 32, 128, 4><<<dim3(128, 3), 256, 0, stream>>>(
        p_f1, p_WfcT, p_bfc, nullptr, nullptr, nullptr, nullptr, (float*)d_out);
}

// Round 12
// 154.670 us; speedup vs baseline: 1.1495x; 1.0549x over previous
//
#include <hip/hip_runtime.h>
#include <math.h>

constexpr int L_ = 2048, D_ = 128, H_ = 16;
constexpr int T_ = 8192;
constexpr int DIN = 80;
constexpr int LDX = T_;              // col-major activations act[chan][token]

typedef __attribute__((ext_vector_type(8))) short short8;   // 8 bf16 (4 VGPR)
typedef __attribute__((ext_vector_type(4))) float floatx4;

// ---- static device globals ----
__device__ float g_xT  [DIN * T_];          // [80][8192]
__device__ float g_posT[D_ * L_];           // [128][2048]
__device__ unsigned short g_h_hi[T_ * D_];  // h bf16-hi, ROW-major [t][k]
__device__ unsigned short g_h_lo[T_ * D_];
__device__ unsigned short g_Wq_hi[3 * D_ * D_];  // in_proj_w bf16x2 [c][k]
__device__ unsigned short g_Wq_lo[3 * D_ * D_];
__device__ float g_qkv [3 * D_ * T_];       // col-major [384][8192]
__device__ unsigned short g_ctxH[T_ * D_];  // ctx bf16x2 ROW-major [t][128]
__device__ unsigned short g_ctxL[T_ * D_];
__device__ unsigned short g_Mf1H[D_ * D_];  // (W1*Wo) bf16x2 row-major [f][d]
__device__ unsigned short g_Mf1L[D_ * D_];
__device__ unsigned short g_MfcH[D_ * D_];  // (Wfc*W2) bf16x2 [o][f], o>=80 zero
__device__ unsigned short g_MfcL[D_ * D_];
__device__ float g_WconvT[DIN * D_];        // [k][o]
__device__ float g_bf1   [D_];
__device__ float g_bfc   [D_];

__device__ __forceinline__ unsigned short bf16h(float x) {      // RNE to bf16
    unsigned u = __float_as_uint(x);
    return (unsigned short)((u + 0x7FFFu + ((u >> 16) & 1u)) >> 16);
}
__device__ __forceinline__ float bf16f(unsigned short h) {
    return __uint_as_float(((unsigned)h) << 16);
}

// ---------------------------------------------------------------------------
// prep: xT transpose | posenc | conv_w transpose | in_proj_w -> bf16x2 |
// fold1 -> M1 bf16x2 + b1' | fold2 -> M2 bf16x2 + b2'.  grid 1000 x 256.
// ---------------------------------------------------------------------------
__global__ __launch_bounds__(256) void prep_kernel(
        const float* __restrict__ x,
        const float* __restrict__ conv_w,
        const float* __restrict__ in_proj_w,
        const float* __restrict__ out_w,  const float* __restrict__ out_b,
        const float* __restrict__ ff_w1,  const float* __restrict__ ff_b1,
        const float* __restrict__ ff_w2,  const float* __restrict__ ff_b2,
        const float* __restrict__ fc_w,   const float* __restrict__ fc_b) {
    __shared__ float smem[80 * 65];
    int bid = blockIdx.x, tid = threadIdx.x;

    if (bid < 128) {                           // x [8192][80] -> xT [80][8192]
        int t0 = bid * 64;
        for (int i = tid; i < 64 * 80; i += 256) {
            int t = i / 80, k = i - t * 80;
            smem[k * 65 + t] = x[(size_t)t0 * 80 + i];
        }
        __syncthreads();
        for (int i = tid; i < 80 * 64; i += 256) {
            int k = i >> 6, tt = i & 63;
            g_xT[(size_t)k * T_ + t0 + tt] = smem[k * 65 + tt];
        }
        return;
    }
    if (bid < 640) {                           // posenc fp32
        int idx = (bid - 128) * 256 + tid;     // [0, 131072)
        int l = idx >> 6, j = idx & 63;
        float inv = __expf((float)j * (-9.210340371976184f / 128.0f));
        float ang = (float)l * inv;
        g_posT[(2 * j) * L_ + l]     = sinf(ang);
        g_posT[(2 * j + 1) * L_ + l] = cosf(ang);
        return;
    }
    if (bid < 680) {                           // conv_w [128][80] -> [80][128]
        int e = (bid - 640) * 256 + tid;
        int o = e / 80, k = e - o * 80;
        g_WconvT[k * D_ + o] = conv_w[e];
        return;
    }
    if (bid < 872) {                           // in_proj_w -> bf16x2 elementwise
        int e = (bid - 680) * 256 + tid;       // [0, 49152)
        float v = in_proj_w[e];
        unsigned short hi = bf16h(v);
        g_Wq_hi[e] = hi;
        g_Wq_lo[e] = bf16h(v - bf16f(hi));
        return;
    }
    float* rowbuf = smem;                      // [2][128]
    float* red = smem + 256;                   // [256]
    if (bid < 936) {                           // fold1: M1=W1*Wo (bf16x2), b1'
        int sub = tid >> 7, k = tid & 127;
        int f = (bid - 872) * 2 + sub;
        rowbuf[sub * 128 + k] = ff_w1[f * 128 + k];
        __syncthreads();
        float acc = 0.f;
#pragma unroll 8
        for (int o = 0; o < 128; o++)
            acc = fmaf(rowbuf[sub * 128 + o], out_w[o * 128 + k], acc);
        unsigned short hi = bf16h(acc);
        g_Mf1H[f * 128 + k] = hi;
        g_Mf1L[f * 128 + k] = bf16h(acc - bf16f(hi));
        red[tid] = rowbuf[sub * 128 + k] * out_b[k];
        __syncthreads();
        for (int s = 64; s > 0; s >>= 1) {
            if (k < s) red[tid] += red[tid + s];
            __syncthreads();
        }
        if (k == 0) g_bf1[f] = red[sub * 128] + ff_b1[f];
        return;
    }
    {                                          // fold2: M2=Wfc*W2 (bf16x2), b2'
        int sub = tid >> 7, k = tid & 127;
        int o = (bid - 936) * 2 + sub;
        rowbuf[sub * 128 + k] = (o < 80) ? fc_w[o * 128 + k] : 0.f;
        __syncthreads();
        float acc = 0.f;
#pragma unroll 8
        for (int d = 0; d < 128; d++)
            acc = fmaf(rowbuf[sub * 128 + d], ff_w2[d * 128 + k], acc);
        unsigned short hi = bf16h(acc);
        g_MfcH[o * 128 + k] = hi;
        g_MfcL[o * 128 + k] = bf16h(acc - bf16f(hi));
        red[tid] = rowbuf[sub * 128 + k] * ff_b2[k];
        __syncthreads();
        for (int s = 64; s > 0; s >>= 1) {
            if (k < s) red[tid] += red[tid + s];
            __syncthreads();
        }
        if (k == 0) g_bfc[o] = (o < 80) ? (red[sub * 128] + fc_b[o]) : 0.f;
        return;
    }
}

// ---------------------------------------------------------------------------
// conv (verbatim R11 EPI=5, proven): fp32 GEMM BM=64 x BN=32, relu+bn+posenc,
// emits h as bf16x2 row-major. grid (128, 4) = 512 blocks.
// ---------------------------------------------------------------------------
__global__ __launch_bounds__(256) void conv_kernel(
        const float* __restrict__ X, const float* __restrict__ Wt,
        const float* __restrict__ bias,
        const float* __restrict__ bg, const float* __restrict__ bb,
        const float* __restrict__ brm, const float* __restrict__ brv) {
    constexpr int BK = 80, BN = 32, TN = 2;
    __shared__ float Xs[BK][64];
    __shared__ float Ws[BK][BN];
    int tid = threadIdx.x;
    int t0 = blockIdx.x * 64;
    int cb = blockIdx.y * BN;
    int tc = tid & 15, tr = tid >> 4;

    float acc[4][TN] = {};
    for (int i = tid; i < BK * 16; i += 256) {
        int k = i >> 4, f = i & 15;
        *(float4*)&Xs[k][f * 4] =
            *(const float4*)&X[(size_t)k * LDX + t0 + f * 4];
    }
    for (int i = tid; i < BK * (BN / 4); i += 256) {
        int k = i / (BN / 4), f = i - k * (BN / 4);
        *(float4*)&Ws[k][f * 4] =
            *(const float4*)&Wt[(size_t)k * D_ + cb + f * 4];
    }
    __syncthreads();
#pragma unroll 4
    for (int k = 0; k < BK; ++k) {
        float4 a = *(float4*)&Xs[k][tr * 4];
        float av[4] = {a.x, a.y, a.z, a.w};
        float wv[TN];
#pragma unroll
        for (int jj = 0; jj < TN; jj++) wv[jj] = Ws[k][tc * TN + jj];
#pragma unroll
        for (int i = 0; i < 4; i++)
#pragma unroll
            for (int jj = 0; jj < TN; jj++)
                acc[i][jj] = fmaf(av[i], wv[jj], acc[i][jj]);
    }

#pragma unroll
    for (int i = 0; i < 4; i++) {
        int t = t0 + tr * 4 + i;
        unsigned hi2 = 0, lo2 = 0;
#pragma unroll
        for (int jj = 0; jj < TN; jj++) {
            int c = cb + tc * TN + jj;
            float v = acc[i][jj] + bias[c];
            v = fmaxf(v, 0.0f);
            v = (v - brm[c]) * (bg[c] * rsqrtf(brv[c] + 1e-5f)) + bb[c];
            v += g_posT[c * L_ + (t & 2047)];
            unsigned short h = bf16h(v);
            float lo = v - bf16f(h);
            hi2 |= ((unsigned)h) << (16 * jj);
            lo2 |= ((unsigned)bf16h(lo)) << (16 * jj);
        }
        int cbase = cb + tc * TN;
        *(unsigned*)&g_h_hi[(size_t)t * 128 + cbase] = hi2;
        *(unsigned*)&g_h_lo[(size_t)t * 128 + cbase] = lo2;
    }
}

// ---------------------------------------------------------------------------
// qkv via MFMA bf16x2 (verbatim R11, proven). grid (256, 6).
// ---------------------------------------------------------------------------
__global__ __launch_bounds__(256) void qkv_mfma(const float* __restrict__ in_proj_b) {
    __shared__ unsigned short WsH[64 * 136];
    __shared__ unsigned short WsL[64 * 136];
    __shared__ unsigned short HsH[32 * 136];
    __shared__ unsigned short HsL[32 * 136];
    int tid = threadIdx.x;
    int t0 = blockIdx.x * 32;
    int cb = blockIdx.y * 64;

    for (int i = tid; i < 1024; i += 256) {
        int r = i >> 4, c8 = (i & 15) * 8;
        *(uint4*)&WsH[r * 136 + c8] = *(const uint4*)&g_Wq_hi[(size_t)(cb + r) * 128 + c8];
        *(uint4*)&WsL[r * 136 + c8] = *(const uint4*)&g_Wq_lo[(size_t)(cb + r) * 128 + c8];
    }
    for (int i = tid; i < 512; i += 256) {
        int r = i >> 4, c8 = (i & 15) * 8;
        *(uint4*)&HsH[r * 136 + c8] = *(const uint4*)&g_h_hi[(size_t)(t0 + r) * 128 + c8];
        *(uint4*)&HsL[r * 136 + c8] = *(const uint4*)&g_h_lo[(size_t)(t0 + r) * 128 + c8];
    }
    __syncthreads();

    int lane = tid & 63, w = tid >> 6;
    int m16 = lane & 15, quad = lane >> 4;
    int c0 = w * 16;

    short8 aH[4], aL[4];
#pragma unroll
    for (int kt = 0; kt < 4; kt++) {
        aH[kt] = *(short8*)&WsH[(c0 + m16) * 136 + kt * 32 + quad * 8];
        aL[kt] = *(short8*)&WsL[(c0 + m16) * 136 + kt * 32 + quad * 8];
    }
    float bias_r[4];
#pragma unroll
    for (int r = 0; r < 4; r++) bias_r[r] = in_proj_b[cb + c0 + quad * 4 + r];

#pragma unroll
    for (int s = 0; s < 2; s++) {
        floatx4 acc = {0.f, 0.f, 0.f, 0.f};
        int trow = s * 16 + m16;
#pragma unroll
        for (int kt = 0; kt < 4; kt++) {
            short8 bH = *(short8*)&HsH[trow * 136 + kt * 32 + quad * 8];
            short8 bL = *(short8*)&HsL[trow * 136 + kt * 32 + quad * 8];
            acc = __builtin_amdgcn_mfma_f32_16x16x32_bf16(aH[kt], bH, acc, 0, 0, 0);
            acc = __builtin_amdgcn_mfma_f32_16x16x32_bf16(aL[kt], bH, acc, 0, 0, 0);
            acc = __builtin_amdgcn_mfma_f32_16x16x32_bf16(aH[kt], bL, acc, 0, 0, 0);
        }
#pragma unroll
        for (int r = 0; r < 4; r++)
            g_qkv[(size_t)(cb + c0 + quad * 4 + r) * LDX + t0 + s * 16 + m16] =
                acc[r] + bias_r[r];
    }
}

// ---------------------------------------------------------------------------
// Attention full-window (R8 proven logic), epilogue -> ctx bf16x2 row-major.
// Block = (bh, 512-q tile), 256 thr, 2 adjacent q/thread. grid (64, 4).
// ---------------------------------------------------------------------------
__global__ __launch_bounds__(256) void attn_kernel() {
    __shared__ float4 SK[2][2][324];
    __shared__ float4 SV[2][2][324];
    int bh = blockIdx.x;
    int qb = blockIdx.y * 512;
    int b = bh >> 4, h = bh & 15;
    int tb = b * L_;
    int tid = threadIdx.x;
    int jbase = qb - 64;

    for (int c16 = 0; c16 < 16; c16++) {
        int d = c16 & 7;
        int ch = ((c16 < 8) ? D_ : 2 * D_) + h * 8 + d;
        const float* src = g_qkv + (size_t)ch * LDX + tb;
        float4* base4 = ((c16 < 8) ? &SK[0][0][0] : &SV[0][0][0]) + (d >> 2) * 324;
        for (int s = tid; s < 641; s += 256) {
            int j = jbase + s;
            float v = ((unsigned)j < (unsigned)L_) ? src[j] : 0.f;
            ((float*)(base4 + (s & 1) * 648 + (s >> 1)))[d & 3] = v;
        }
    }
    __syncthreads();

    const float sc = 0.35355339059327373f;      // 1/sqrt(8)
    int q0 = qb + 2 * tid;
    float qa[8], qc[8];
#pragma unroll
    for (int d = 0; d < 8; d++) {
        qa[d] = g_qkv[(size_t)(h * 8 + d) * LDX + tb + q0] * sc;
        qc[d] = g_qkv[(size_t)(h * 8 + d) * LDX + tb + q0 + 1] * sc;
    }
    float l0 = 0.f, l1 = 0.f;
    float A0[8] = {}, A1[8] = {};
    int j00 = jbase + 2 * tid;

#pragma unroll 2
    for (int it = 0; it <= 129; it++) {
        int pp = it & 1, idx = tid + (it >> 1);
        float4 ka = SK[pp][0][idx], kb2 = SK[pp][1][idx];
        float kv[8] = {ka.x, ka.y, ka.z, ka.w, kb2.x, kb2.y, kb2.z, kb2.w};
        float s0 = 0.f, s1 = 0.f;
#pragma unroll
        for (int d = 0; d < 8; d++) {
            s0 = fmaf(qa[d], kv[d], s0);
            s1 = fmaf(qc[d], kv[d], s1);
        }
        bool jv = (unsigned)(j00 + it) < (unsigned)L_;
        float w0 = (jv && it != 64 && it <= 128) ? __expf(s0) : 0.f;
        float w1 = (jv && it != 65 && it >= 1)  ? __expf(s1) : 0.f;
        l0 += w0; l1 += w1;
        float4 va = SV[pp][0][idx], vb2 = SV[pp][1][idx];
        float vv[8] = {va.x, va.y, va.z, va.w, vb2.x, vb2.y, vb2.z, vb2.w};
#pragma unroll
        for (int d = 0; d < 8; d++) {
            A0[d] = fmaf(w0, vv[d], A0[d]);
            A1[d] = fmaf(w1, vv[d], A1[d]);
        }
    }
    float i0 = 1.f / l0, i1 = 1.f / l1;
    // ctx bf16x2 row-major [t][128]; this block owns channels h*8..h*8+7
    unsigned hp[4], lp[4];
#pragma unroll
    for (int d2 = 0; d2 < 4; d2++) {
        float v0 = A0[2 * d2] * i0, v1 = A0[2 * d2 + 1] * i0;
        unsigned short h0 = bf16h(v0), h1 = bf16h(v1);
        hp[d2] = (unsigned)h0 | ((unsigned)h1 << 16);
        lp[d2] = (unsigned)bf16h(v0 - bf16f(h0)) |
                 ((unsigned)bf16h(v1 - bf16f(h1)) << 16);
    }
    *(uint4*)&g_ctxH[(size_t)(tb + q0) * 128 + h * 8] = *(uint4*)hp;
    *(uint4*)&g_ctxL[(size_t)(tb + q0) * 128 + h * 8] = *(uint4*)lp;
#pragma unroll
    for (int d2 = 0; d2 < 4; d2++) {
        float v0 = A1[2 * d2] * i1, v1 = A1[2 * d2 + 1] * i1;
        unsigned short h0 = bf16h(v0), h1 = bf16h(v1);
        hp[d2] = (unsigned)h0 | ((unsigned)h1 << 16);
        lp[d2] = (unsigned)bf16h(v0 - bf16f(h0)) |
                 ((unsigned)bf16h(v1 - bf16f(h1)) << 16);
    }
    *(uint4*)&g_ctxH[(size_t)(tb + q0 + 1) * 128 + h * 8] = *(uint4*)hp;
    *(uint4*)&g_ctxL[(size_t)(tb + q0 + 1) * 128 + h * 8] = *(uint4*)lp;
}

// ---------------------------------------------------------------------------
// Fused tail via MFMA bf16x2: C1 = relu(ctx*M1^T + b1') -> LDS bf16x2, then
// out = C1*M2^T + b2' -> row-major [t][80]. Block = 32 tokens, 4 waves:
// wave w owns f/o-range [w*32, w*32+32). 256 blocks.
// ---------------------------------------------------------------------------
__global__ __launch_bounds__(256) void f1fc_mfma(float* __restrict__ out) {
    __shared__ unsigned short sm[4 * 32 * 136];   // ctxH|ctxL|C1H|C1L
    unsigned short* ctxH = sm;
    unsigned short* ctxL = sm + 32 * 136;
    unsigned short* C1H  = sm + 2 * 32 * 136;
    unsigned short* C1L  = sm + 3 * 32 * 136;
    float* C2 = (float*)sm;                       // aliases ctx region (phase 3)
    __shared__ float b1s[128];

    int tid = threadIdx.x;
    int t0 = blockIdx.x * 32;

    for (int i = tid; i < 512; i += 256) {        // stage ctx planes
        int r = i >> 4, c8 = (i & 15) * 8;
        *(uint4*)&ctxH[r * 136 + c8] = *(const uint4*)&g_ctxH[(size_t)(t0 + r) * 128 + c8];
        *(uint4*)&ctxL[r * 136 + c8] = *(const uint4*)&g_ctxL[(size_t)(t0 + r) * 128 + c8];
    }
    if (tid < 128) b1s[tid] = g_bf1[tid];
    __syncthreads();

    int lane = tid & 63, w = tid >> 6;
    int m16 = lane & 15, quad = lane >> 4;

    // ---- phase 1: C1[f][t], f in [w*32, w*32+32) ----
    floatx4 acc1[2][2];
#pragma unroll
    for (int mt = 0; mt < 2; mt++) {
        int fbase = w * 32 + mt * 16 + m16;
        short8 aH[4], aL[4];
#pragma unroll
        for (int kt = 0; kt < 4; kt++) {
            aH[kt] = *(const short8*)&g_Mf1H[(size_t)fbase * 128 + kt * 32 + quad * 8];
            aL[kt] = *(const short8*)&g_Mf1L[(size_t)fbase * 128 + kt * 32 + quad * 8];
        }
#pragma unroll
        for (int nt = 0; nt < 2; nt++) {
            floatx4 acc = {0.f, 0.f, 0.f, 0.f};
            int trow = nt * 16 + m16;
#pragma unroll
            for (int kt = 0; kt < 4; kt++) {
                short8 bH = *(short8*)&ctxH[trow * 136 + kt * 32 + quad * 8];
                short8 bL = *(short8*)&ctxL[trow * 136 + kt * 32 + quad * 8];
                acc = __builtin_amdgcn_mfma_f32_16x16x32_bf16(aH[kt], bH, acc, 0, 0, 0);
                acc = __builtin_amdgcn_mfma_f32_16x16x32_bf16(aL[kt], bH, acc, 0, 0, 0);
                acc = __builtin_amdgcn_mfma_f32_16x16x32_bf16(aH[kt], bL, acc, 0, 0, 0);
            }
            acc1[mt][nt] = acc;
        }
    }
    // write C1 (relu + b1') as bf16x2 to LDS, layout [t][f]
#pragma unroll
    for (int mt = 0; mt < 2; mt++) {
#pragma unroll
        for (int nt = 0; nt < 2; nt++) {
            int f0 = w * 32 + mt * 16 + quad * 4;
            int t = nt * 16 + m16;
            float v[4];
#pragma unroll
            for (int r = 0; r < 4; r++)
                v[r] = fmaxf(acc1[mt][nt][r] + b1s[f0 + r], 0.f);
            unsigned short h0 = bf16h(v[0]), h1 = bf16h(v[1]);
            unsigned short h2 = bf16h(v[2]), h3 = bf16h(v[3]);
            *(unsigned*)&C1H[t * 136 + f0]     = (unsigned)h0 | ((unsigned)h1 << 16);
            *(unsigned*)&C1H[t * 136 + f0 + 2] = (unsigned)h2 | ((unsigned)h3 << 16);
            *(unsigned*)&C1L[t * 136 + f0] =
                (unsigned)bf16h(v[0] - bf16f(h0)) | ((unsigned)bf16h(v[1] - bf16f(h1)) << 16);
            *(unsigned*)&C1L[t * 136 + f0 + 2] =
                (unsigned)bf16h(v[2] - bf16f(h2)) | ((unsigned)bf16h(v[3] - bf16f(h3)) << 16);
        }
    }
    __syncthreads();

    // ---- phase 2: C2[o][t], o in [w*32, w*32+32) (o>=96 discarded) ----
    floatx4 acc2[2][2];
#pragma unroll
    for (int mt = 0; mt < 2; mt++) {
        int obase = w * 32 + mt * 16 + m16;
        short8 aH[4], aL[4];
#pragma unroll
        for (int kt = 0; kt < 4; kt++) {
            aH[kt] = *(const short8*)&g_MfcH[(size_t)obase * 128 + kt * 32 + quad * 8];
            aL[kt] = *(const short8*)&g_MfcL[(size_t)obase * 128 + kt * 32 + quad * 8];
        }
#pragma unroll
        for (int nt = 0; nt < 2; nt++) {
            floatx4 acc = {0.f, 0.f, 0.f, 0.f};
            int trow = nt * 16 + m16;
#pragma unroll
            for (int kt = 0; kt < 4; kt++) {
                short8 bH = *(short8*)&C1H[trow * 136 + kt * 32 + quad * 8];
                short8 bL = *(short8*)&C1L[trow * 136 + kt * 32 + quad * 8];
                acc = __builtin_amdgcn_mfma_f32_16x16x32_bf16(aH[kt], bH, acc, 0, 0, 0);
                acc = __builtin_amdgcn_mfma_f32_16x16x32_bf16(aL[kt], bH, acc, 0, 0, 0);
                acc = __builtin_amdgcn_mfma_f32_16x16x32_bf16(aH[kt], bL, acc, 0, 0, 0);
            }
            acc2[mt][nt] = acc;
        }
    }
    __syncthreads();                              // all C1 reads done; reuse ctx region
    // C2 fp32 -> LDS [t][100] for o<96, then coalesced store
#pragma unroll
    for (int mt = 0; mt < 2; mt++) {
        int o0 = w * 32 + mt * 16 + quad * 4;
        if (o0 < 96) {
#pragma unroll
            for (int nt = 0; nt < 2; nt++) {
                int t = nt * 16 + m16;
#pragma unroll
                for (int r = 0; r < 4; r++)
                    C2[t * 100 + o0 + r] = acc2[mt][nt][r] + g_bfc[o0 + r];
            }
        }
    }
    __syncthreads();
    for (int i = tid; i < 640; i += 256) {        // 32 tok x 20 float4
        int t = i / 20, c4 = i - t * 20;
        *(float4*)&out[(size_t)(t0 + t) * 80 + c4 * 4] = *(float4*)&C2[t * 100 + c4 * 4];
    }
}

// ---------------------------------------------------------------------------
extern "C" void kernel_launch(void* const* d_in, const int* in_sizes, int n_in,
                              void* d_out, int out_size, void* d_ws, size_t ws_size,
                              hipStream_t stream) {
    const float* x         = (const float*)d_in[0];
    const float* conv_w    = (const float*)d_in[1];
    const float* conv_b    = (const float*)d_in[2];
    const float* bn_g      = (const float*)d_in[3];
    const float* bn_b      = (const float*)d_in[4];
    const float* bn_rm     = (const float*)d_in[5];
    const float* bn_rv     = (const float*)d_in[6];
    const float* in_proj_w = (const float*)d_in[7];
    const float* in_proj_b = (const float*)d_in[8];
    const float* out_w     = (const float*)d_in[9];
    const float* out_b     = (const float*)d_in[10];
    const float* ff_w1     = (const float*)d_in[11];
    const float* ff_b1     = (const float*)d_in[12];
    const float* ff_w2     = (const float*)d_in[13];
    const float* ff_b2     = (const float*)d_in[14];
    const float* fc_w      = (const float*)d_in[15];
    const float* fc_b      = (const float*)d_in[16];

    float *p_xT, *p_WconvT;
    hipGetSymbolAddress((void**)&p_xT,     HIP_SYMBOL(g_xT));
    hipGetSymbolAddress((void**)&p_WconvT, HIP_SYMBOL(g_WconvT));

    prep_kernel<<<1000, 256, 0, stream>>>(x, conv_w, in_proj_w, out_w, out_b,
                                          ff_w1, ff_b1, ff_w2, ff_b2, fc_w, fc_b);

    // conv+relu+bn+pos -> h bf16x2 row-major: 512 blocks
    conv_kernel<<<dim3(128, 4), 256, 0, stream>>>(
        p_xT, p_WconvT, conv_b, bn_g, bn_b, bn_rm, bn_rv);

    // qkv via MFMA bf16x2: 1536 blocks
    qkv_mfma<<<dim3(256, 6), 256, 0, stream>>>(in_proj_b);

    // full-window attention -> ctx bf16x2: 256 blocks
    attn_kernel<<<dim3(64, 4), 256, 0, stream>>>();

    // fused MFMA tail -> row-major [t][80]: 256 blocks
    f1fc_mfma<<<256, 256, 0, stream>>>((float*)d_out);
}

// Round 13
// 146.697 us; speedup vs baseline: 1.2120x; 1.0543x over previous
//
#include <hip/hip_runtime.h>
#include <math.h>

constexpr int L_ = 2048, D_ = 128, H_ = 16;
constexpr int T_ = 8192;
constexpr int LDX = T_;              // col-major activations act[chan][token]

typedef __attribute__((ext_vector_type(8))) short short8;   // 8 bf16 (4 VGPR)
typedef __attribute__((ext_vector_type(4))) float floatx4;

// ---- static device globals ----
__device__ unsigned short g_h_hi[T_ * D_];  // h bf16-hi, ROW-major [t][k]
__device__ unsigned short g_h_lo[T_ * D_];
__device__ unsigned short g_Wq_hi[3 * D_ * D_];  // in_proj_w bf16x2 [c][k]
__device__ unsigned short g_Wq_lo[3 * D_ * D_];
__device__ float g_qkv [3 * D_ * T_];       // col-major [384][8192]
__device__ unsigned short g_ctxH[T_ * D_];  // ctx bf16x2 ROW-major [t][128]
__device__ unsigned short g_ctxL[T_ * D_];
__device__ unsigned short g_Mf1H[D_ * D_];  // (W1*Wo) bf16x2 row-major [f][d]
__device__ unsigned short g_Mf1L[D_ * D_];
__device__ unsigned short g_MfcH[D_ * D_];  // (Wfc*W2) bf16x2 [o][f], o>=80 zero
__device__ unsigned short g_MfcL[D_ * D_];
__device__ float g_bf1 [D_];
__device__ float g_bfc [D_];

__device__ __forceinline__ unsigned short bf16h(float x) {      // RNE to bf16
    unsigned u = __float_as_uint(x);
    return (unsigned short)((u + 0x7FFFu + ((u >> 16) & 1u)) >> 16);
}
__device__ __forceinline__ float bf16f(unsigned short h) {
    return __uint_as_float(((unsigned)h) << 16);
}

// ---------------------------------------------------------------------------
// stage1: bid<256 conv-MFMA (inline x->bf16x2, global W frags, inline posenc)
//         | 256-303 in_proj_w -> bf16x2 | 304-367 fold1 | 368-431 fold2.
// Dissolves the old prep dispatch. grid 432 x 256.
// ---------------------------------------------------------------------------
__global__ __launch_bounds__(256) void stage1_kernel(
        const float* __restrict__ x, const float* __restrict__ conv_w,
        const float* __restrict__ conv_b,
        const float* __restrict__ bg, const float* __restrict__ bb,
        const float* __restrict__ brm, const float* __restrict__ brv,
        const float* __restrict__ in_proj_w,
        const float* __restrict__ out_w,  const float* __restrict__ out_b,
        const float* __restrict__ ff_w1,  const float* __restrict__ ff_b1,
        const float* __restrict__ ff_w2,  const float* __restrict__ ff_b2,
        const float* __restrict__ fc_w,   const float* __restrict__ fc_b) {
    __shared__ unsigned short sm[2 * 32 * 104];   // 13.3 KB; folds alias as float
    int bid = blockIdx.x, tid = threadIdx.x;

    if (bid < 256) {                               // ---- conv via MFMA ----
        unsigned short* XsH = sm;                  // [32][104], k padded to 96
        unsigned short* XsL = sm + 32 * 104;
        int t0 = bid * 32;

        for (int p = tid; p < 1280; p += 256) {    // x -> bf16x2 planes
            int f0 = p * 2;
            int r = f0 / 80, k = f0 - r * 80;      // pairs never straddle rows
            float2 v2 = *(const float2*)&x[(size_t)(t0 + r) * 80 + k];
            unsigned short h0 = bf16h(v2.x), h1 = bf16h(v2.y);
            *(unsigned*)&XsH[r * 104 + k] = (unsigned)h0 | ((unsigned)h1 << 16);
            *(unsigned*)&XsL[r * 104 + k] =
                (unsigned)bf16h(v2.x - bf16f(h0)) |
                ((unsigned)bf16h(v2.y - bf16f(h1)) << 16);
        }
        for (int i = tid; i < 384; i += 256) {     // zero pad k in [80,104)
            int r = i / 12, k = 80 + 2 * (i - r * 12);
            *(unsigned*)&XsH[r * 104 + k] = 0u;
            *(unsigned*)&XsL[r * 104 + k] = 0u;
        }
        __syncthreads();

        int lane = tid & 63, w = tid >> 6;
        int m16 = lane & 15, quad = lane >> 4;

        // A fragments: conv_w fp32 -> bf16x2 in-register, zero for k>=80
        short8 aH[2][3], aL[2][3];
#pragma unroll
        for (int mt = 0; mt < 2; mt++) {
            int c = w * 32 + mt * 16 + m16;
#pragma unroll
            for (int kt = 0; kt < 3; kt++) {
                int kb = kt * 32 + quad * 8;
                short8 vh = {0, 0, 0, 0, 0, 0, 0, 0};
                short8 vl = {0, 0, 0, 0, 0, 0, 0, 0};
                if (kb < 80) {
                    float4 f0 = *(const float4*)&conv_w[(size_t)c * 80 + kb];
                    float4 f1 = *(const float4*)&conv_w[(size_t)c * 80 + kb + 4];
                    float vv[8] = {f0.x, f0.y, f0.z, f0.w, f1.x, f1.y, f1.z, f1.w};
#pragma unroll
                    for (int e = 0; e < 8; e++) {
                        unsigned short hh = bf16h(vv[e]);
                        vh[e] = (short)hh;
                        vl[e] = (short)bf16h(vv[e] - bf16f(hh));
                    }
                }
                aH[mt][kt] = vh; aL[mt][kt] = vl;
            }
        }

#pragma unroll
        for (int mt = 0; mt < 2; mt++) {
#pragma unroll
            for (int nt = 0; nt < 2; nt++) {
                floatx4 acc = {0.f, 0.f, 0.f, 0.f};
                int trow = nt * 16 + m16;
#pragma unroll
                for (int kt = 0; kt < 3; kt++) {
                    short8 bHv = *(short8*)&XsH[trow * 104 + kt * 32 + quad * 8];
                    short8 bLv = *(short8*)&XsL[trow * 104 + kt * 32 + quad * 8];
                    acc = __builtin_amdgcn_mfma_f32_16x16x32_bf16(aH[mt][kt], bHv, acc, 0, 0, 0);
                    acc = __builtin_amdgcn_mfma_f32_16x16x32_bf16(aL[mt][kt], bHv, acc, 0, 0, 0);
                    acc = __builtin_amdgcn_mfma_f32_16x16x32_bf16(aH[mt][kt], bLv, acc, 0, 0, 0);
                }
                // epilogue: bias + relu + BN + inline posenc -> h bf16x2
                int c0 = w * 32 + mt * 16 + quad * 4;
                int t = t0 + nt * 16 + m16;
                int l = t & 2047;
                float vr[4];
#pragma unroll
                for (int r = 0; r < 4; r++) {
                    int c = c0 + r;
                    float v = acc[r] + conv_b[c];
                    v = fmaxf(v, 0.0f);
                    v = (v - brm[c]) * (bg[c] * rsqrtf(brv[c] + 1e-5f)) + bb[c];
                    float inv = __expf((float)(c >> 1) * (-9.210340371976184f / 128.0f));
                    float ang = (float)l * inv;
                    v += (c & 1) ? cosf(ang) : sinf(ang);
                    vr[r] = v;
                }
                unsigned short h0 = bf16h(vr[0]), h1 = bf16h(vr[1]);
                unsigned short h2 = bf16h(vr[2]), h3 = bf16h(vr[3]);
                unsigned hp[2] = {(unsigned)h0 | ((unsigned)h1 << 16),
                                  (unsigned)h2 | ((unsigned)h3 << 16)};
                unsigned lp[2] = {
                    (unsigned)bf16h(vr[0] - bf16f(h0)) | ((unsigned)bf16h(vr[1] - bf16f(h1)) << 16),
                    (unsigned)bf16h(vr[2] - bf16f(h2)) | ((unsigned)bf16h(vr[3] - bf16f(h3)) << 16)};
                *(uint2*)&g_h_hi[(size_t)t * 128 + c0] = *(uint2*)hp;
                *(uint2*)&g_h_lo[(size_t)t * 128 + c0] = *(uint2*)lp;
            }
        }
        return;
    }
    if (bid < 304) {                               // ---- in_proj_w -> bf16x2 ----
        int e4 = ((bid - 256) * 256 + tid) * 4;    // [0, 49152) step 4
        float4 v = *(const float4*)&in_proj_w[e4];
        float vv[4] = {v.x, v.y, v.z, v.w};
        unsigned short hh[4], ll[4];
#pragma unroll
        for (int e = 0; e < 4; e++) {
            hh[e] = bf16h(vv[e]);
            ll[e] = bf16h(vv[e] - bf16f(hh[e]));
        }
        unsigned hp[2] = {(unsigned)hh[0] | ((unsigned)hh[1] << 16),
                          (unsigned)hh[2] | ((unsigned)hh[3] << 16)};
        unsigned lp[2] = {(unsigned)ll[0] | ((unsigned)ll[1] << 16),
                          (unsigned)ll[2] | ((unsigned)ll[3] << 16)};
        *(uint2*)&g_Wq_hi[e4] = *(uint2*)hp;
        *(uint2*)&g_Wq_lo[e4] = *(uint2*)lp;
        return;
    }
    float* rowbuf = (float*)sm;                    // [2][128]
    float* red = (float*)sm + 256;                 // [256]
    if (bid < 368) {                               // ---- fold1 ----
        int sub = tid >> 7, k = tid & 127;
        int f = (bid - 304) * 2 + sub;
        rowbuf[sub * 128 + k] = ff_w1[f * 128 + k];
        __syncthreads();
        float acc = 0.f;
#pragma unroll 8
        for (int o = 0; o < 128; o++)
            acc = fmaf(rowbuf[sub * 128 + o], out_w[o * 128 + k], acc);
        unsigned short hi = bf16h(acc);
        g_Mf1H[f * 128 + k] = hi;
        g_Mf1L[f * 128 + k] = bf16h(acc - bf16f(hi));
        red[tid] = rowbuf[sub * 128 + k] * out_b[k];
        __syncthreads();
        for (int s = 64; s > 0; s >>= 1) {
            if (k < s) red[tid] += red[tid + s];
            __syncthreads();
        }
        if (k == 0) g_bf1[f] = red[sub * 128] + ff_b1[f];
        return;
    }
    {                                              // ---- fold2 ----
        int sub = tid >> 7, k = tid & 127;
        int o = (bid - 368) * 2 + sub;
        rowbuf[sub * 128 + k] = (o < 80) ? fc_w[o * 128 + k] : 0.f;
        __syncthreads();
        float acc = 0.f;
#pragma unroll 8
        for (int d = 0; d < 128; d++)
            acc = fmaf(rowbuf[sub * 128 + d], ff_w2[d * 128 + k], acc);
        unsigned short hi = bf16h(acc);
        g_MfcH[o * 128 + k] = hi;
        g_MfcL[o * 128 + k] = bf16h(acc - bf16f(hi));
        red[tid] = rowbuf[sub * 128 + k] * ff_b2[k];
        __syncthreads();
        for (int s = 64; s > 0; s >>= 1) {
            if (k < s) red[tid] += red[tid + s];
            __syncthreads();
        }
        if (k == 0) g_bfc[o] = (o < 80) ? (red[sub * 128] + fc_b[o]) : 0.f;
        return;
    }
}

// ---------------------------------------------------------------------------
// qkv via MFMA bf16x2 (verbatim R12, proven). grid (256, 6).
// ---------------------------------------------------------------------------
__global__ __launch_bounds__(256) void qkv_mfma(const float* __restrict__ in_proj_b) {
    __shared__ unsigned short WsH[64 * 136];
    __shared__ unsigned short WsL[64 * 136];
    __shared__ unsigned short HsH[32 * 136];
    __shared__ unsigned short HsL[32 * 136];
    int tid = threadIdx.x;
    int t0 = blockIdx.x * 32;
    int cb = blockIdx.y * 64;

    for (int i = tid; i < 1024; i += 256) {
        int r = i >> 4, c8 = (i & 15) * 8;
        *(uint4*)&WsH[r * 136 + c8] = *(const uint4*)&g_Wq_hi[(size_t)(cb + r) * 128 + c8];
        *(uint4*)&WsL[r * 136 + c8] = *(const uint4*)&g_Wq_lo[(size_t)(cb + r) * 128 + c8];
    }
    for (int i = tid; i < 512; i += 256) {
        int r = i >> 4, c8 = (i & 15) * 8;
        *(uint4*)&HsH[r * 136 + c8] = *(const uint4*)&g_h_hi[(size_t)(t0 + r) * 128 + c8];
        *(uint4*)&HsL[r * 136 + c8] = *(const uint4*)&g_h_lo[(size_t)(t0 + r) * 128 + c8];
    }
    __syncthreads();

    int lane = tid & 63, w = tid >> 6;
    int m16 = lane & 15, quad = lane >> 4;
    int c0 = w * 16;

    short8 aH[4], aL[4];
#pragma unroll
    for (int kt = 0; kt < 4; kt++) {
        aH[kt] = *(short8*)&WsH[(c0 + m16) * 136 + kt * 32 + quad * 8];
        aL[kt] = *(short8*)&WsL[(c0 + m16) * 136 + kt * 32 + quad * 8];
    }
    float bias_r[4];
#pragma unroll
    for (int r = 0; r < 4; r++) bias_r[r] = in_proj_b[cb + c0 + quad * 4 + r];

#pragma unroll
    for (int s = 0; s < 2; s++) {
        floatx4 acc = {0.f, 0.f, 0.f, 0.f};
        int trow = s * 16 + m16;
#pragma unroll
        for (int kt = 0; kt < 4; kt++) {
            short8 bH = *(short8*)&HsH[trow * 136 + kt * 32 + quad * 8];
            short8 bL = *(short8*)&HsL[trow * 136 + kt * 32 + quad * 8];
            acc = __builtin_amdgcn_mfma_f32_16x16x32_bf16(aH[kt], bH, acc, 0, 0, 0);
            acc = __builtin_amdgcn_mfma_f32_16x16x32_bf16(aL[kt], bH, acc, 0, 0, 0);
            acc = __builtin_amdgcn_mfma_f32_16x16x32_bf16(aH[kt], bL, acc, 0, 0, 0);
        }
#pragma unroll
        for (int r = 0; r < 4; r++)
            g_qkv[(size_t)(cb + c0 + quad * 4 + r) * LDX + t0 + s * 16 + m16] =
                acc[r] + bias_r[r];
    }
}

// ---------------------------------------------------------------------------
// Attention full-window (verbatim R12, proven), -> ctx bf16x2 row-major.
// ---------------------------------------------------------------------------
__global__ __launch_bounds__(256) void attn_kernel() {
    __shared__ float4 SK[2][2][324];
    __shared__ float4 SV[2][2][324];
    int bh = blockIdx.x;
    int qb = blockIdx.y * 512;
    int b = bh >> 4, h = bh & 15;
    int tb = b * L_;
    int tid = threadIdx.x;
    int jbase = qb - 64;

    for (int c16 = 0; c16 < 16; c16++) {
        int d = c16 & 7;
        int ch = ((c16 < 8) ? D_ : 2 * D_) + h * 8 + d;
        const float* src = g_qkv + (size_t)ch * LDX + tb;
        float4* base4 = ((c16 < 8) ? &SK[0][0][0] : &SV[0][0][0]) + (d >> 2) * 324;
        for (int s = tid; s < 641; s += 256) {
            int j = jbase + s;
            float v = ((unsigned)j < (unsigned)L_) ? src[j] : 0.f;
            ((float*)(base4 + (s & 1) * 648 + (s >> 1)))[d & 3] = v;
        }
    }
    __syncthreads();

    const float sc = 0.35355339059327373f;      // 1/sqrt(8)
    int q0 = qb + 2 * tid;
    float qa[8], qc[8];
#pragma unroll
    for (int d = 0; d < 8; d++) {
        qa[d] = g_qkv[(size_t)(h * 8 + d) * LDX + tb + q0] * sc;
        qc[d] = g_qkv[(size_t)(h * 8 + d) * LDX + tb + q0 + 1] * sc;
    }
    float l0 = 0.f, l1 = 0.f;
    float A0[8] = {}, A1[8] = {};
    int j00 = jbase + 2 * tid;

#pragma unroll 2
    for (int it = 0; it <= 129; it++) {
        int pp = it & 1, idx = tid + (it >> 1);
        float4 ka = SK[pp][0][idx], kb2 = SK[pp][1][idx];
        float kv[8] = {ka.x, ka.y, ka.z, ka.w, kb2.x, kb2.y, kb2.z, kb2.w};
        float s0 = 0.f, s1 = 0.f;
#pragma unroll
        for (int d = 0; d < 8; d++) {
            s0 = fmaf(qa[d], kv[d], s0);
            s1 = fmaf(qc[d], kv[d], s1);
        }
        bool jv = (unsigned)(j00 + it) < (unsigned)L_;
        float w0 = (jv && it != 64 && it <= 128) ? __expf(s0) : 0.f;
        float w1 = (jv && it != 65 && it >= 1)  ? __expf(s1) : 0.f;
        l0 += w0; l1 += w1;
        float4 va = SV[pp][0][idx], vb2 = SV[pp][1][idx];
        float vv[8] = {va.x, va.y, va.z, va.w, vb2.x, vb2.y, vb2.z, vb2.w};
#pragma unroll
        for (int d = 0; d < 8; d++) {
            A0[d] = fmaf(w0, vv[d], A0[d]);
            A1[d] = fmaf(w1, vv[d], A1[d]);
        }
    }
    float i0 = 1.f / l0, i1 = 1.f / l1;
    unsigned hp[4], lp[4];
#pragma unroll
    for (int d2 = 0; d2 < 4; d2++) {
        float v0 = A0[2 * d2] * i0, v1 = A0[2 * d2 + 1] * i0;
        unsigned short h0 = bf16h(v0), h1 = bf16h(v1);
        hp[d2] = (unsigned)h0 | ((unsigned)h1 << 16);
        lp[d2] = (unsigned)bf16h(v0 - bf16f(h0)) |
                 ((unsigned)bf16h(v1 - bf16f(h1)) << 16);
    }
    *(uint4*)&g_ctxH[(size_t)(tb + q0) * 128 + h * 8] = *(uint4*)hp;
    *(uint4*)&g_ctxL[(size_t)(tb + q0) * 128 + h * 8] = *(uint4*)lp;
#pragma unroll
    for (int d2 = 0; d2 < 4; d2++) {
        float v0 = A1[2 * d2] * i1, v1 = A1[2 * d2 + 1] * i1;
        unsigned short h0 = bf16h(v0), h1 = bf16h(v1);
        hp[d2] = (unsigned)h0 | ((unsigned)h1 << 16);
        lp[d2] = (unsigned)bf16h(v0 - bf16f(h0)) |
                 ((unsigned)bf16h(v1 - bf16f(h1)) << 16);
    }
    *(uint4*)&g_ctxH[(size_t)(tb + q0 + 1) * 128 + h * 8] = *(uint4*)hp;
    *(uint4*)&g_ctxL[(size_t)(tb + q0 + 1) * 128 + h * 8] = *(uint4*)lp;
}

// ---------------------------------------------------------------------------
// Fused tail via MFMA bf16x2 (verbatim R12, proven). 256 blocks.
// ---------------------------------------------------------------------------
__global__ __launch_bounds__(256) void f1fc_mfma(float* __restrict__ out) {
    __shared__ unsigned short sm[4 * 32 * 136];   // ctxH|ctxL|C1H|C1L
    unsigned short* ctxH = sm;
    unsigned short* ctxL = sm + 32 * 136;
    unsigned short* C1H  = sm + 2 * 32 * 136;
    unsigned short* C1L  = sm + 3 * 32 * 136;
    float* C2 = (float*)sm;
    __shared__ float b1s[128];

    int tid = threadIdx.x;
    int t0 = blockIdx.x * 32;

    for (int i = tid; i < 512; i += 256) {
        int r = i >> 4, c8 = (i & 15) * 8;
        *(uint4*)&ctxH[r * 136 + c8] = *(const uint4*)&g_ctxH[(size_t)(t0 + r) * 128 + c8];
        *(uint4*)&ctxL[r * 136 + c8] = *(const uint4*)&g_ctxL[(size_t)(t0 + r) * 128 + c8];
    }
    if (tid < 128) b1s[tid] = g_bf1[tid];
    __syncthreads();

    int lane = tid & 63, w = tid >> 6;
    int m16 = lane & 15, quad = lane >> 4;

    floatx4 acc1[2][2];
#pragma unroll
    for (int mt = 0; mt < 2; mt++) {
        int fbase = w * 32 + mt * 16 + m16;
        short8 aH[4], aL[4];
#pragma unroll
        for (int kt = 0; kt < 4; kt++) {
            aH[kt] = *(const short8*)&g_Mf1H[(size_t)fbase * 128 + kt * 32 + quad * 8];
            aL[kt] = *(const short8*)&g_Mf1L[(size_t)fbase * 128 + kt * 32 + quad * 8];
        }
#pragma unroll
        for (int nt = 0; nt < 2; nt++) {
            floatx4 acc = {0.f, 0.f, 0.f, 0.f};
            int trow = nt * 16 + m16;
#pragma unroll
            for (int kt = 0; kt < 4; kt++) {
                short8 bH = *(short8*)&ctxH[trow * 136 + kt * 32 + quad * 8];
                short8 bL = *(short8*)&ctxL[trow * 136 + kt * 32 + quad * 8];
                acc = __builtin_amdgcn_mfma_f32_16x16x32_bf16(aH[kt], bH, acc, 0, 0, 0);
                acc = __builtin_amdgcn_mfma_f32_16x16x32_bf16(aL[kt], bH, acc, 0, 0, 0);
                acc = __builtin_amdgcn_mfma_f32_16x16x32_bf16(aH[kt], bL, acc, 0, 0, 0);
            }
            acc1[mt][nt] = acc;
        }
    }
#pragma unroll
    for (int mt = 0; mt < 2; mt++) {
#pragma unroll
        for (int nt = 0; nt < 2; nt++) {
            int f0 = w * 32 + mt * 16 + quad * 4;
            int t = nt * 16 + m16;
            float v[4];
#pragma unroll
            for (int r = 0; r < 4; r++)
                v[r] = fmaxf(acc1[mt][nt][r] + b1s[f0 + r], 0.f);
            unsigned short h0 = bf16h(v[0]), h1 = bf16h(v[1]);
            unsigned short h2 = bf16h(v[2]), h3 = bf16h(v[3]);
            *(unsigned*)&C1H[t * 136 + f0]     = (unsigned)h0 | ((unsigned)h1 << 16);
            *(unsigned*)&C1H[t * 136 + f0 + 2] = (unsigned)h2 | ((unsigned)h3 << 16);
            *(unsigned*)&C1L[t * 136 + f0] =
                (unsigned)bf16h(v[0] - bf16f(h0)) | ((unsigned)bf16h(v[1] - bf16f(h1)) << 16);
            *(unsigned*)&C1L[t * 136 + f0 + 2] =
                (unsigned)bf16h(v[2] - bf16f(h2)) | ((unsigned)bf16h(v[3] - bf16f(h3)) << 16);
        }
    }
    __syncthreads();

    floatx4 acc2[2][2];
#pragma unroll
    for (int mt = 0; mt < 2; mt++) {
        int obase = w * 32 + mt * 16 + m16;
        short8 aH[4], aL[4];
#pragma unroll
        for (int kt = 0; kt < 4; kt++) {
            aH[kt] = *(const short8*)&g_MfcH[(size_t)obase * 128 + kt * 32 + quad * 8];
            aL[kt] = *(const short8*)&g_MfcL[(size_t)obase * 128 + kt * 32 + quad * 8];
        }
#pragma unroll
        for (int nt = 0; nt < 2; nt++) {
            floatx4 acc = {0.f, 0.f, 0.f, 0.f};
            int trow = nt * 16 + m16;
#pragma unroll
            for (int kt = 0; kt < 4; kt++) {
                short8 bH = *(short8*)&C1H[trow * 136 + kt * 32 + quad * 8];
                short8 bL = *(short8*)&C1L[trow * 136 + kt * 32 + quad * 8];
                acc = __builtin_amdgcn_mfma_f32_16x16x32_bf16(aH[kt], bH, acc, 0, 0, 0);
                acc = __builtin_amdgcn_mfma_f32_16x16x32_bf16(aL[kt], bH, acc, 0, 0, 0);
                acc = __builtin_amdgcn_mfma_f32_16x16x32_bf16(aH[kt], bL, acc, 0, 0, 0);
            }
            acc2[mt][nt] = acc;
        }
    }
    __syncthreads();
#pragma unroll
    for (int mt = 0; mt < 2; mt++) {
        int o0 = w * 32 + mt * 16 + quad * 4;
        if (o0 < 96) {
#pragma unroll
            for (int nt = 0; nt < 2; nt++) {
                int t = nt * 16 + m16;
#pragma unroll
                for (int r = 0; r < 4; r++)
                    C2[t * 100 + o0 + r] = acc2[mt][nt][r] + g_bfc[o0 + r];
            }
        }
    }
    __syncthreads();
    for (int i = tid; i < 640; i += 256) {
        int t = i / 20, c4 = i - t * 20;
        *(float4*)&out[(size_t)(t0 + t) * 80 + c4 * 4] = *(float4*)&C2[t * 100 + c4 * 4];
    }
}

// ---------------------------------------------------------------------------
extern "C" void kernel_launch(void* const* d_in, const int* in_sizes, int n_in,
                              void* d_out, int out_size, void* d_ws, size_t ws_size,
                              hipStream_t stream) {
    const float* x         = (const float*)d_in[0];
    const float* conv_w    = (const float*)d_in[1];
    const float* conv_b    = (const float*)d_in[2];
    const float* bn_g      = (const float*)d_in[3];
    const float* bn_b      = (const float*)d_in[4];
    const float* bn_rm     = (const float*)d_in[5];
    const float* bn_rv     = (const float*)d_in[6];
    const float* in_proj_w = (const float*)d_in[7];
    const float* in_proj_b = (const float*)d_in[8];
    const float* out_w     = (const float*)d_in[9];
    const float* out_b     = (const float*)d_in[10];
    const float* ff_w1     = (const float*)d_in[11];
    const float* ff_b1     = (const float*)d_in[12];
    const float* ff_w2     = (const float*)d_in[13];
    const float* ff_b2     = (const float*)d_in[14];
    const float* fc_w      = (const float*)d_in[15];
    const float* fc_b      = (const float*)d_in[16];

    // conv MFMA + Wq conversion + folds, one dispatch
    stage1_kernel<<<432, 256, 0, stream>>>(x, conv_w, conv_b, bn_g, bn_b,
                                           bn_rm, bn_rv, in_proj_w,
                                           out_w, out_b, ff_w1, ff_b1,
                                           ff_w2, ff_b2, fc_w, fc_b);

    // qkv via MFMA bf16x2: 1536 blocks
    qkv_mfma<<<dim3(256, 6), 256, 0, stream>>>(in_proj_b);

    // full-window attention -> ctx bf16x2: 256 blocks
    attn_kernel<<<dim3(64, 4), 256, 0, stream>>>();

    // fused MFMA tail -> row-major [t][80]: 256 blocks
    f1fc_mfma<<<256, 256, 0, stream>>>((float*)d_out);
}